// Round 1
// baseline (80.056 us; speedup 1.0000x reference)
//
#include <hip/hip_runtime.h>

// Problem: B=128, H=W=28 (HW=784), C=128.
// reference: per-(b,c) spatial argmax of x -> gather t_p[c, h*, w*, :, :]
// -> outputs (relu(x*t), x, t) each [B,H,W,C], concatenated in d_out.

constexpr int Hc = 28, Wc = 28, HWc = 784, Cc = 128, Bc = 128;

// ---------------------------------------------------------------------------
// K1: partial argmax per (b, c) over a spatial chunk.
// grid = B * SCH blocks, 1024 threads. Thread t: c = t&127, part = t>>7 (8
// parts per chunk). Lane i reads channel i => fully coalesced 256B/wave.
// Strict '>' keeps the FIRST max (JAX argmax tie semantics); parts/chunks are
// ordered by increasing s, so the LDS combine also uses strict '>'.
// ---------------------------------------------------------------------------
__global__ __launch_bounds__(1024) void argmax_part_kernel(
    const float* __restrict__ x, float* __restrict__ pmax,
    int* __restrict__ pidx, int sch) {
  int blk = blockIdx.x;
  int b = blk / sch;
  int chunk = blk - b * sch;
  int t = threadIdx.x;
  int c = t & (Cc - 1);
  int part = t >> 7;                 // 0..7
  int per = HWc / (8 * sch);         // 49 (sch=2) or 98 (sch=1)
  int s0 = chunk * (HWc / sch) + part * per;

  const float* xp = x + (size_t)b * HWc * Cc + c;
  float best = -3.4e38f;
  int bi = s0;
  for (int k = 0; k < per; ++k) {
    int s = s0 + k;
    float v = xp[(size_t)s * Cc];
    if (v > best) { best = v; bi = s; }
  }

  __shared__ float smax[8][Cc];
  __shared__ int sidx[8][Cc];
  smax[part][c] = best;
  sidx[part][c] = bi;
  __syncthreads();

  if (t < Cc) {
    float m = smax[0][t];
    int mi = sidx[0][t];
#pragma unroll
    for (int p = 1; p < 8; ++p) {
      float v = smax[p][t];
      if (v > m) { m = v; mi = sidx[p][t]; }   // strict >: keep earliest s
    }
    int o = (b * sch + chunk) * Cc + t;
    pmax[o] = m;
    pidx[o] = mi;
  }
}

// ---------------------------------------------------------------------------
// K2: finalize argmax (reduce sch partials), then produce all three outputs.
// grid = (7, B); block handles b = blockIdx.y, s in [blockIdx.x*112, +112).
// Thread t: c4 = t&31 (owns channels 4*c4..4*c4+3), soff = t>>5 (0..7),
// loops k=0..13 over s = sbase + soff + 8k.
// x load / all stores are float4 coalesced; t_p is a 4B gather from 4 rows,
// but each 64B line is reused 16x within the block's s-range (L1-resident).
// ---------------------------------------------------------------------------
__global__ __launch_bounds__(256) void fused_out_kernel(
    const float* __restrict__ x, const float* __restrict__ tp,
    const float* __restrict__ pmax, const int* __restrict__ pidx, int sch,
    float* __restrict__ out) {
  int b = blockIdx.y;
  int t = threadIdx.x;

  __shared__ unsigned tbase[Cc];   // per-channel t_p row base (fits in u32)
  if (t < Cc) {
    int base = b * sch * Cc + t;
    float m = pmax[base];
    int mi = pidx[base];
    for (int p = 1; p < sch; ++p) {
      float v = pmax[base + p * Cc];
      if (v > m) { m = v; mi = pidx[base + p * Cc]; }
    }
    tbase[t] = (unsigned)(t * HWc + mi) * (unsigned)HWc;
  }
  __syncthreads();

  int c4 = t & 31;
  int soff = t >> 5;                       // 0..7
  int sbase = blockIdx.x * 112;
  int ch = c4 << 2;

  const float* r0 = tp + tbase[ch + 0];
  const float* r1 = tp + tbase[ch + 1];
  const float* r2 = tp + tbase[ch + 2];
  const float* r3 = tp + tbase[ch + 3];

  const size_t plane = (size_t)HWc * Cc;   // 100352
  float* om = out;
  float* ox = out + (size_t)Bc * plane;
  float* ot = out + 2 * (size_t)Bc * plane;

#pragma unroll 2
  for (int k = 0; k < 14; ++k) {
    int s = sbase + soff + (k << 3);
    size_t off = (size_t)b * plane + (size_t)s * Cc + ch;

    float4 xv = *(const float4*)(x + off);
    float4 tv;
    tv.x = r0[s];
    tv.y = r1[s];
    tv.z = r2[s];
    tv.w = r3[s];

    float4 mv;
    mv.x = fmaxf(xv.x * tv.x, 0.f);
    mv.y = fmaxf(xv.y * tv.y, 0.f);
    mv.z = fmaxf(xv.z * tv.z, 0.f);
    mv.w = fmaxf(xv.w * tv.w, 0.f);

    *(float4*)(om + off) = mv;
    *(float4*)(ox + off) = xv;
    *(float4*)(ot + off) = tv;
  }
}

extern "C" void kernel_launch(void* const* d_in, const int* in_sizes, int n_in,
                              void* d_out, int out_size, void* d_ws,
                              size_t ws_size, hipStream_t stream) {
  const float* x = (const float*)d_in[0];
  const float* tp = (const float*)d_in[1];
  float* out = (float*)d_out;

  // workspace: pmax[B*sch*C] floats + pidx[B*sch*C] ints
  int sch = 2;
  if (ws_size < (size_t)Bc * 2 * Cc * 8) sch = 1;   // fallback (needs 128KB)
  float* pmax = (float*)d_ws;
  int* pidx = (int*)((char*)d_ws + (size_t)Bc * sch * Cc * sizeof(float));

  argmax_part_kernel<<<dim3(Bc * sch), 1024, 0, stream>>>(x, pmax, pidx, sch);
  fused_out_kernel<<<dim3(7, Bc), 256, 0, stream>>>(x, tp, pmax, pidx, sch, out);
}

// Round 2
// 57.759 us; speedup vs baseline: 1.3860x; 1.3860x over previous
//
#include <hip/hip_runtime.h>

// B=128, H=W=28 (HW=784), C=128.
// ref: per-(b,c) spatial argmax of x -> gather t_p[c, h*, w*] (a [28,28] tile)
// -> outputs (relu(x*t), x, t) each [B,H,W,C], concatenated in d_out.

constexpr int HWc = 784, Cc = 128, Bc = 128;

typedef float f4 __attribute__((ext_vector_type(4)));
typedef int i4 __attribute__((ext_vector_type(4)));

__device__ inline void nt_store(float* p, f4 v) {
  __builtin_nontemporal_store(v, (f4*)p);
}

// ---------------------------------------------------------------------------
// K1: partial argmax per (b,c) over half the spatial range, float4 over c.
// grid = B*2, block = 256. Thread: c4 = t&31 (channels 4c4..4c4+3),
// part = t>>5 (8 parts x 49 s). Wave reads 2x512B contiguous segments/instr.
// Strict '>' in ascending-s order preserves JAX first-max tie semantics.
// ---------------------------------------------------------------------------
__global__ __launch_bounds__(256) void argmax_part_kernel(
    const float* __restrict__ x, float* __restrict__ pmax,
    int* __restrict__ pidx) {
  int blk = blockIdx.x;
  int b = blk >> 1;
  int chunk = blk & 1;
  int t = threadIdx.x;
  int c4 = t & 31;
  int part = t >> 5;
  int s0 = chunk * 392 + part * 49;

  const float* xp = x + (size_t)b * HWc * Cc + (c4 << 2);
  const f4* p = (const f4*)(xp + (size_t)s0 * Cc);

  f4 best = {-3.4e38f, -3.4e38f, -3.4e38f, -3.4e38f};
  i4 bi = {s0, s0, s0, s0};
  for (int k = 0; k < 49; ++k) {
    f4 v = *p;
    p += Cc / 4;  // next s
    int s = s0 + k;
    if (v[0] > best[0]) { best[0] = v[0]; bi[0] = s; }
    if (v[1] > best[1]) { best[1] = v[1]; bi[1] = s; }
    if (v[2] > best[2]) { best[2] = v[2]; bi[2] = s; }
    if (v[3] > best[3]) { best[3] = v[3]; bi[3] = s; }
  }

  __shared__ float smax[8][Cc];
  __shared__ int sidx[8][Cc];
  *(f4*)&smax[part][c4 << 2] = best;
  *(i4*)&sidx[part][c4 << 2] = bi;
  __syncthreads();

  if (t < Cc) {
    float m = smax[0][t];
    int mi = sidx[0][t];
#pragma unroll
    for (int pp = 1; pp < 8; ++pp) {
      float v = smax[pp][t];
      if (v > m) { m = v; mi = sidx[pp][t]; }  // strict >: earliest s wins
    }
    int o = (b * 2 + chunk) * Cc + t;
    pmax[o] = m;
    pidx[o] = mi;
  }
}

// ---------------------------------------------------------------------------
// K2: finalize argmax (2 partials), then produce all three outputs.
// grid = (7, B), block = 256. Thread: c4 = t&31, u = t>>5 (0..7).
// Register tile = 4s x 4c per iteration: 4 float4 x-loads (2x512B segments),
// 4 float4 t-loads ALONG s (wave: 32 rows x 2 same-line offsets = 32 lines
// per 1KB useful), transpose in registers, 12 float4 nontemporal stores.
// idx = 8k+u covers the block's 28 s4-groups (k=3 only for u<4; the guard is
// wave-uniform since u is constant per half... per 32-lane group and both u
// values in a wave fall on the same side of 4 only for waves 0/1 vs 2/3).
// ---------------------------------------------------------------------------
__global__ __launch_bounds__(256) void fused_out_kernel(
    const float* __restrict__ x, const float* __restrict__ tp,
    const float* __restrict__ pmax, const int* __restrict__ pidx,
    float* __restrict__ out) {
  int b = blockIdx.y;
  int t = threadIdx.x;

  __shared__ int tbase[Cc];  // per-channel t_p row base in floats (<2^31)
  if (t < Cc) {
    int base = b * 2 * Cc + t;
    float m = pmax[base];
    int mi = pidx[base];
    float v = pmax[base + Cc];
    if (v > m) { m = v; mi = pidx[base + Cc]; }
    tbase[t] = (t * HWc + mi) * HWc;
  }
  __syncthreads();

  int c4 = t & 31;
  int u = t >> 5;
  int ch = c4 << 2;

  const float* r0 = tp + tbase[ch + 0];
  const float* r1 = tp + tbase[ch + 1];
  const float* r2 = tp + tbase[ch + 2];
  const float* r3 = tp + tbase[ch + 3];

  const size_t plane = (size_t)HWc * Cc;  // 100352
  size_t bplane = (size_t)b * plane;
  float* om = out;
  float* ox = out + (size_t)Bc * plane;
  float* ot = out + 2 * (size_t)Bc * plane;
  int sb = blockIdx.x * 112;

  for (int k = 0; k < 4; ++k) {
    int idx = 8 * k + u;
    if (idx < 28) {
      int s0 = sb + (idx << 2);
      size_t off = bplane + (size_t)s0 * Cc + ch;
      const float* xp = x + off;

      f4 xv0 = *(const f4*)(xp);
      f4 xv1 = *(const f4*)(xp + Cc);
      f4 xv2 = *(const f4*)(xp + 2 * Cc);
      f4 xv3 = *(const f4*)(xp + 3 * Cc);
      f4 tv0 = *(const f4*)(r0 + s0);
      f4 tv1 = *(const f4*)(r1 + s0);
      f4 tv2 = *(const f4*)(r2 + s0);
      f4 tv3 = *(const f4*)(r3 + s0);

      float* omp = om + off;
      float* oxp = ox + off;
      float* otp = ot + off;

#pragma unroll
      for (int i = 0; i < 4; ++i) {
        f4 xvi = (i == 0) ? xv0 : (i == 1) ? xv1 : (i == 2) ? xv2 : xv3;
        f4 tcol = {tv0[i], tv1[i], tv2[i], tv3[i]};
        f4 mv;
        mv[0] = fmaxf(xvi[0] * tcol[0], 0.f);
        mv[1] = fmaxf(xvi[1] * tcol[1], 0.f);
        mv[2] = fmaxf(xvi[2] * tcol[2], 0.f);
        mv[3] = fmaxf(xvi[3] * tcol[3], 0.f);
        nt_store(omp + i * Cc, mv);
        nt_store(oxp + i * Cc, xvi);
        nt_store(otp + i * Cc, tcol);
      }
    }
  }
}

extern "C" void kernel_launch(void* const* d_in, const int* in_sizes, int n_in,
                              void* d_out, int out_size, void* d_ws,
                              size_t ws_size, hipStream_t stream) {
  const float* x = (const float*)d_in[0];
  const float* tp = (const float*)d_in[1];
  float* out = (float*)d_out;

  // workspace: pmax[B*2*C] floats + pidx[B*2*C] ints = 256 KB
  float* pmax = (float*)d_ws;
  int* pidx = (int*)((char*)d_ws + (size_t)Bc * 2 * Cc * sizeof(float));

  argmax_part_kernel<<<dim3(Bc * 2), 256, 0, stream>>>(x, pmax, pidx);
  fused_out_kernel<<<dim3(7, Bc), 256, 0, stream>>>(x, tp, pmax, pidx, out);
}